// Round 13
// baseline (629.431 us; speedup 1.0000x reference)
//
#include <hip/hip_runtime.h>
#include <math.h>

#define NB    512
#define FDIM  80
#define LEN   111
#define TDEC  222
#define CFDIM 32
#define EOS   113   // eoT row stride: coprime with 32 banks -> conflict-free

typedef float v2 __attribute__((ext_vector_type(2)));
typedef float v4 __attribute__((ext_vector_type(4)));

__device__ __forceinline__ float rcpf(float x){ return __builtin_amdgcn_rcpf(x); }
__device__ __forceinline__ float sigm(float x){ return rcpf(1.0f + __expf(-x)); }
// tanh(x) = 1 - 2/(e^{2x}+1): valid for |x| < 40 (our args are < ~6)
__device__ __forceinline__ float ftanh(float x){
  float e = __expf(2.0f*x);
  return 1.0f - 2.0f*rcpf(e + 1.0f);
}

template<int CTRL, int ROW_MASK>
__device__ __forceinline__ float dpp_add(float x){
  int yi = __builtin_amdgcn_update_dpp(0, __builtin_bit_cast(int, x), CTRL, ROW_MASK, 0xf, false);
  return x + __builtin_bit_cast(float, yi);
}
__device__ __forceinline__ float wave_sum(float x){
  x = dpp_add<0x111, 0xf>(x);
  x = dpp_add<0x112, 0xf>(x);
  x = dpp_add<0x114, 0xf>(x);
  x = dpp_add<0x118, 0xf>(x);
  x = dpp_add<0x142, 0xa>(x);  // row_bcast:15
  x = dpp_add<0x143, 0xc>(x);  // row_bcast:31
  return __builtin_bit_cast(float, __builtin_amdgcn_readlane(__builtin_bit_cast(int, x), 63));
}
#define RL(x, u) __builtin_bit_cast(float, __builtin_amdgcn_readlane(__builtin_bit_cast(int, (x)), (u)))

__global__ __launch_bounds__(64, 1)
void attn_rnn_kernel(const float* __restrict__ g_in,
                     const float* __restrict__ enc_Wx, const float* __restrict__ enc_Wh, const float* __restrict__ enc_b,
                     const float* __restrict__ att_Wq, const float* __restrict__ att_bq,
                     const float* __restrict__ att_Wm, const float* __restrict__ att_bm,
                     const float* __restrict__ att_V,  const float* __restrict__ att_bv,
                     const float* __restrict__ loc_Wc, const float* __restrict__ loc_Wd,
                     const float* __restrict__ dec_Wx, const float* __restrict__ dec_Wh, const float* __restrict__ dec_b,
                     const float* __restrict__ out_W,  const float* __restrict__ out_b,
                     float* __restrict__ g_out)
{
  __shared__ float xp[LEN*80];
  __shared__ float eoT[20*EOS];
  __shared__ float Wm_s[200];

  const int lane = threadIdx.x;
  const int b    = blockIdx.x;
  const float* inp = g_in + (size_t)b * LEN * FDIM;

  for (int k = lane; k < 200; k += 64) Wm_s[k] = att_Wm[k];

  float V[10], wloc[10], bmv[10];
  #pragma unroll
  for (int a = 0; a < 10; a++){ V[a] = att_V[a]; bmv[a] = att_bm[a]; wloc[a] = 0.f; }
  for (int cf = 0; cf < CFDIM; ++cf){
    float lwc = loc_Wc[cf];
    #pragma unroll
    for (int a = 0; a < 10; a++) wloc[a] += lwc * loc_Wd[cf*10 + a];
  }
  const float bv = att_bv[0];
  const float ob = out_b[0];
  const float bq_l = att_bq[(lane < 10) ? lane : 0];
  const float outw = (lane < 20) ? out_W[lane] : 0.f;
  // scores fold: sum_a V_a*tanh(pre_a) = SV - 2*sum_a V_a*rcp(e^{2pre_a}+1)
  float SB = bv;
  #pragma unroll
  for (int a = 0; a < 10; a++) SB += V[a];

  // ---- xp prologue: xp[t][j] = x[t].Wx[:,j] + b[j] ----
  {
    float wxc[80];
    #pragma unroll
    for (int i = 0; i < 80; i++) wxc[i] = enc_Wx[i*80 + lane];
    const float ebj = enc_b[lane];
    for (int t = 0; t < LEN; t++){
      const float* xr = inp + t*FDIM;
      float a0=0.f,a1=0.f,a2=0.f,a3=0.f;
      #pragma unroll
      for (int i = 0; i < 80; i += 4){
        a0 += xr[i  ]*wxc[i  ]; a1 += xr[i+1]*wxc[i+1];
        a2 += xr[i+2]*wxc[i+2]; a3 += xr[i+3]*wxc[i+3];
      }
      xp[t*80 + lane] = ebj + ((a0+a1)+(a2+a3));
    }
  }
  {
    const int col = 64 + (lane >> 2);
    float wxc[80];
    #pragma unroll
    for (int i = 0; i < 80; i++) wxc[i] = enc_Wx[i*80 + col];
    const float ebj = enc_b[col];
    for (int t = (lane & 3); t < LEN; t += 4){
      const float* xr = inp + t*FDIM;
      float a0=0.f,a1=0.f,a2=0.f,a3=0.f;
      #pragma unroll
      for (int i = 0; i < 80; i += 4){
        a0 += xr[i  ]*wxc[i  ]; a1 += xr[i+1]*wxc[i+1];
        a2 += xr[i+2]*wxc[i+2]; a3 += xr[i+3]*wxc[i+3];
      }
      xp[t*80 + col] = ebj + ((a0+a1)+(a2+a3));
    }
  }

  // gate-major layout: lane u (<20) owns ALL FOUR gates {i,f,g,o} of unit u.
  // Weight quads: {W[u'][u], W[u'][u+20], W[u'][u+40], W[u'][u+60]} per lane.
  const int u0 = (lane < 20) ? lane : 0;   // clamped (lanes>=20 compute garbage, masked later)
  v4 wh4[20];
  #pragma unroll
  for (int u = 0; u < 20; u++)
    wh4[u] = (v4){ enc_Wh[u*80 + u0], enc_Wh[u*80 + u0+20], enc_Wh[u*80 + u0+40], enc_Wh[u*80 + u0+60] };
  __syncthreads();                         // [barrier 1/2] xp + Wm_s ready

  // ================= encoder: barrier-free, bpermute-free =================
  float s_h[20];
  #pragma unroll
  for (int u = 0; u < 20; u++) s_h[u] = 0.f;
  float c_enc = 0.f;
  for (int t = 0; t < LEN; t++){
    // z quad for unit u0 (4-way split chains, 5-deep each)
    v4 ac0 = (v4){ xp[t*80 + u0], xp[t*80 + u0+20], xp[t*80 + u0+40], xp[t*80 + u0+60] };
    v4 ac1 = (v4)(0.f), ac2 = (v4)(0.f), ac3 = (v4)(0.f);
    #pragma unroll
    for (int u = 0; u < 20; u += 4){
      ac0 += s_h[u  ]*wh4[u  ];
      ac1 += s_h[u+1]*wh4[u+1];
      ac2 += s_h[u+2]*wh4[u+2];
      ac3 += s_h[u+3]*wh4[u+3];
    }
    v4 z = (ac0 + ac1) + (ac2 + ac3);      // {zi, zf, zg, zo} — all lane-local
    float hval = 0.f;
    if (lane < 20){
      c_enc = sigm(z.y)*c_enc + sigm(z.x)*ftanh(z.z);
      hval  = sigm(z.w)*ftanh(c_enc);
      eoT[lane*EOS + t] = hval;
    }
    #pragma unroll
    for (int u = 0; u < 20; u++) s_h[u] = RL(hval, u);
  }
  __syncthreads();                         // [barrier 2/2] eoT ready

  // ---- per-lane eo rows + mem_proj rows -> registers ----
  const int l1 = (lane < 47) ? lane + 64 : lane;
  float er0[20], er1[20];
  #pragma unroll
  for (int u = 0; u < 20; u++){ er0[u] = eoT[u*EOS + lane]; er1[u] = eoT[u*EOS + l1]; }
  float mp0[10], mp1[10];
  #pragma unroll
  for (int a = 0; a < 10; a++){
    float m0 = bmv[a], m1 = bmv[a];
    #pragma unroll
    for (int u = 0; u < 20; u++){ m0 += er0[u]*Wm_s[u*10 + a]; m1 += er1[u]*Wm_s[u*10 + a]; }
    mp0[a] = m0; mp1[a] = m1;
  }

  // ---- decoder weight quads ----
  v4 dwx4[20], dwh4[20];
  #pragma unroll
  for (int u = 0; u < 20; u++){
    dwx4[u] = (v4){ dec_Wx[u*80 + u0], dec_Wx[u*80 + u0+20], dec_Wx[u*80 + u0+40], dec_Wx[u*80 + u0+60] };
    dwh4[u] = (v4){ dec_Wh[u*80 + u0], dec_Wh[u*80 + u0+20], dec_Wh[u*80 + u0+40], dec_Wh[u*80 + u0+60] };
  }
  const v4 db4 = (v4){ dec_b[u0], dec_b[u0+20], dec_b[u0+40], dec_b[u0+60] };
  float wq[20];
  if (lane < 10){
    #pragma unroll
    for (int u = 0; u < 20; u++) wq[u] = att_Wq[u*10 + lane];
  }

  float s_c[20];
  #pragma unroll
  for (int u = 0; u < 20; u++){ s_c[u] = 0.f; s_h[u] = 0.f; }

  // ================= decoder: barrier-free, bpermute-free =================
  float ap0 = 0.f, ap1 = 0.f, c_dec = 0.f;
  for (int t = 0; t < TDEC; t++){
    // q = c @ att_Wq + bq (query from CELL state, per reference)
    float qv = bq_l;
    if (lane < 10){
      float qa = 0.f, qb = 0.f;
      #pragma unroll
      for (int u = 0; u < 20; u += 2){ qa += s_c[u]*wq[u]; qb += s_c[u+1]*wq[u+1]; }
      qv += qa + qb;
    }
    float s_q[10];
    #pragma unroll
    for (int a = 0; a < 10; a++) s_q[a] = RL(qv, a);

    // scores: sc = SB - 2*sum_a V_a * rcp(exp(2*pre_a)+1)   (inline loc-tanh)
    float r00 = 0.f, r01 = 0.f, r10 = 0.f, r11 = 0.f;
    #pragma unroll
    for (int a = 0; a < 10; a += 2){
      float pre0 = mp0[a]   + s_q[a]   + ftanh(wloc[a]*ap0);
      float pre1 = mp1[a]   + s_q[a]   + ftanh(wloc[a]*ap1);
      float pr20 = mp0[a+1] + s_q[a+1] + ftanh(wloc[a+1]*ap0);
      float pr21 = mp1[a+1] + s_q[a+1] + ftanh(wloc[a+1]*ap1);
      r00 += V[a]  *rcpf(__expf(2.0f*pre0) + 1.0f);
      r01 += V[a]  *rcpf(__expf(2.0f*pre1) + 1.0f);
      r10 += V[a+1]*rcpf(__expf(2.0f*pr20) + 1.0f);
      r11 += V[a+1]*rcpf(__expf(2.0f*pr21) + 1.0f);
    }
    // |sc| <= |bv|+sum|V| (~2): exp cannot overflow -> no max subtraction
    float e0 = __expf(SB - 2.0f*(r00 + r10));
    float e1 = (lane < 47) ? __expf(SB - 2.0f*(r01 + r11)) : 0.f;
    float inv = rcpf(wave_sum(e0 + e1));
    ap0 = e0*inv; ap1 = e1*inv;

    // ctx raw reduces (20 independent DPP trees; inv folded at the end)
    float ws[20];
    #pragma unroll
    for (int u = 0; u < 20; u++) ws[u] = wave_sum(e0*er0[u] + e1*er1[u]);

    // z quad = ctx@Wx + h@Wh + b: 2-way split chains, all lane-local
    v4 zx0 = (v4)(0.f), zx1 = (v4)(0.f);
    v4 zh0 = db4,        zh1 = (v4)(0.f);
    #pragma unroll
    for (int u = 0; u < 20; u += 2){
      zx0 += ws[u]   *dwx4[u];
      zx1 += ws[u+1] *dwx4[u+1];
      zh0 += s_h[u]  *dwh4[u];
      zh1 += s_h[u+1]*dwh4[u+1];
    }
    v4 zzh = zh0 + zh1;
    v4 zzx = zx0 + zx1;
    v4 z;
    z.x = zzh.x + zzx.x*inv;
    z.y = zzh.y + zzx.y*inv;
    z.z = zzh.z + zzx.z*inv;
    z.w = zzh.w + zzx.w*inv;

    float hval = 0.f;
    if (lane < 20){
      c_dec = sigm(z.y)*c_dec + sigm(z.x)*ftanh(z.z);
      hval  = sigm(z.w)*ftanh(c_dec);
    }

    // state broadcast (feeds next step's q and zh)
    #pragma unroll
    for (int u = 0; u < 20; u++){ s_c[u] = RL(c_dec, u); s_h[u] = RL(hval, u); }

    // y output (dead-end, drains under next step's issue)
    float pv = wave_sum(hval*outw);
    if (lane == 0) g_out[(size_t)b*TDEC + t] = ftanh(pv + ob);
  }
}

extern "C" void kernel_launch(void* const* d_in, const int* in_sizes, int n_in,
                              void* d_out, int out_size, void* d_ws, size_t ws_size,
                              hipStream_t stream) {
  const float* g_in   = (const float*)d_in[0];
  const float* enc_Wx = (const float*)d_in[1];
  const float* enc_Wh = (const float*)d_in[2];
  const float* enc_b  = (const float*)d_in[3];
  const float* att_Wq = (const float*)d_in[4];
  const float* att_bq = (const float*)d_in[5];
  const float* att_Wm = (const float*)d_in[6];
  const float* att_bm = (const float*)d_in[7];
  const float* att_V  = (const float*)d_in[8];
  const float* att_bv = (const float*)d_in[9];
  const float* loc_Wc = (const float*)d_in[10];
  const float* loc_Wd = (const float*)d_in[11];
  const float* dec_Wx = (const float*)d_in[12];
  const float* dec_Wh = (const float*)d_in[13];
  const float* dec_b  = (const float*)d_in[14];
  const float* out_W  = (const float*)d_in[15];
  const float* out_b  = (const float*)d_in[16];
  float* g_out = (float*)d_out;

  hipLaunchKernelGGL(attn_rnn_kernel, dim3(NB), dim3(64), 0, stream,
                     g_in, enc_Wx, enc_Wh, enc_b, att_Wq, att_bq, att_Wm, att_bm,
                     att_V, att_bv, loc_Wc, loc_Wd, dec_Wx, dec_Wh, dec_b,
                     out_W, out_b, g_out);
}

// Round 14
// 569.870 us; speedup vs baseline: 1.1045x; 1.1045x over previous
//
#include <hip/hip_runtime.h>
#include <math.h>

#define NB    512
#define FDIM  80
#define LEN   111
#define TDEC  222
#define CFDIM 32
#define EOS   113   // eoT row stride: coprime with 32 banks -> conflict-free

typedef float v2 __attribute__((ext_vector_type(2)));

__device__ __forceinline__ float rcpf(float x){ return __builtin_amdgcn_rcpf(x); }
__device__ __forceinline__ float sigm(float x){ return rcpf(1.0f + __expf(-x)); }
// tanh(x) = 1 - 2/(e^{2x}+1): valid for |x| < 40 (our args are < ~6)
__device__ __forceinline__ float ftanh(float x){
  float e = __expf(2.0f*x);
  return 1.0f - 2.0f*rcpf(e + 1.0f);
}

template<int CTRL, int ROW_MASK>
__device__ __forceinline__ float dpp_add(float x){
  int yi = __builtin_amdgcn_update_dpp(0, __builtin_bit_cast(int, x), CTRL, ROW_MASK, 0xf, false);
  return x + __builtin_bit_cast(float, yi);
}
__device__ __forceinline__ float wave_sum(float x){
  x = dpp_add<0x111, 0xf>(x);
  x = dpp_add<0x112, 0xf>(x);
  x = dpp_add<0x114, 0xf>(x);
  x = dpp_add<0x118, 0xf>(x);
  x = dpp_add<0x142, 0xa>(x);  // row_bcast:15
  x = dpp_add<0x143, 0xc>(x);  // row_bcast:31
  return __builtin_bit_cast(float, __builtin_amdgcn_readlane(__builtin_bit_cast(int, x), 63));
}
#define RL(x, u) __builtin_bit_cast(float, __builtin_amdgcn_readlane(__builtin_bit_cast(int, (x)), (u)))

__global__ __launch_bounds__(64, 1)
void attn_rnn_kernel(const float* __restrict__ g_in,
                     const float* __restrict__ enc_Wx, const float* __restrict__ enc_Wh, const float* __restrict__ enc_b,
                     const float* __restrict__ att_Wq, const float* __restrict__ att_bq,
                     const float* __restrict__ att_Wm, const float* __restrict__ att_bm,
                     const float* __restrict__ att_V,  const float* __restrict__ att_bv,
                     const float* __restrict__ loc_Wc, const float* __restrict__ loc_Wd,
                     const float* __restrict__ dec_Wx, const float* __restrict__ dec_Wh, const float* __restrict__ dec_b,
                     const float* __restrict__ out_W,  const float* __restrict__ out_b,
                     float* __restrict__ g_out)
{
  __shared__ float xp[LEN*80];
  __shared__ float eoT[20*EOS];
  __shared__ float Wm_s[200];

  const int lane = threadIdx.x;
  const int b    = blockIdx.x;
  const float* inp = g_in + (size_t)b * LEN * FDIM;

  for (int k = lane; k < 200; k += 64) Wm_s[k] = att_Wm[k];

  float V[10], wloc[10], bmv[10];
  #pragma unroll
  for (int a = 0; a < 10; a++){ V[a] = att_V[a]; bmv[a] = att_bm[a]; wloc[a] = 0.f; }
  for (int cf = 0; cf < CFDIM; ++cf){
    float lwc = loc_Wc[cf];
    #pragma unroll
    for (int a = 0; a < 10; a++) wloc[a] += lwc * loc_Wd[cf*10 + a];
  }
  const float bv = att_bv[0];
  const float ob = out_b[0];
  const float bq_l = att_bq[(lane < 10) ? lane : 0];
  const float outw = (lane < 20) ? out_W[lane] : 0.f;
  // scores fold: sum_a V_a*tanh(pre_a) = SV - 2*sum_a V_a*rcp(e^{2pre_a}+1)
  float SB = bv;
  #pragma unroll
  for (int a = 0; a < 10; a++) SB += V[a];

  // ---- xp prologue: xp[t][j] = x[t].Wx[:,j] + b[j] ----
  {
    float wxc[80];
    #pragma unroll
    for (int i = 0; i < 80; i++) wxc[i] = enc_Wx[i*80 + lane];
    const float ebj = enc_b[lane];
    for (int t = 0; t < LEN; t++){
      const float* xr = inp + t*FDIM;
      float a0=0.f,a1=0.f,a2=0.f,a3=0.f;
      #pragma unroll
      for (int i = 0; i < 80; i += 4){
        a0 += xr[i  ]*wxc[i  ]; a1 += xr[i+1]*wxc[i+1];
        a2 += xr[i+2]*wxc[i+2]; a3 += xr[i+3]*wxc[i+3];
      }
      xp[t*80 + lane] = ebj + ((a0+a1)+(a2+a3));
    }
  }
  {
    const int col = 64 + (lane >> 2);
    float wxc[80];
    #pragma unroll
    for (int i = 0; i < 80; i++) wxc[i] = enc_Wx[i*80 + col];
    const float ebj = enc_b[col];
    for (int t = (lane & 3); t < LEN; t += 4){
      const float* xr = inp + t*FDIM;
      float a0=0.f,a1=0.f,a2=0.f,a3=0.f;
      #pragma unroll
      for (int i = 0; i < 80; i += 4){
        a0 += xr[i  ]*wxc[i  ]; a1 += xr[i+1]*wxc[i+1];
        a2 += xr[i+2]*wxc[i+2]; a3 += xr[i+3]*wxc[i+3];
      }
      xp[t*80 + col] = ebj + ((a0+a1)+(a2+a3));
    }
  }

  // Pair layout: lane u (<20) owns cols {u, u+20} = {zi,zf};
  //              lane u+32     owns cols {u+40, u+60} = {zg,zo}.
  // Cross-lane handoff is a half-wave swap (shfl_xor 32) -> VALU permlane.
  const int ur = lane & 31;
  const int u0 = (ur < 20) ? ur : 0;       // clamped for inactive lanes
  const int cA = (lane >= 32) ? (u0 + 40) : u0;
  const int cB = cA + 20;
  v2 whp[20];
  #pragma unroll
  for (int u = 0; u < 20; u++)
    whp[u] = (v2){ enc_Wh[u*80 + cA], enc_Wh[u*80 + cB] };
  __syncthreads();                         // [barrier 1/2] xp + Wm_s ready

  // ================= encoder: barrier-free =================
  float s_h[20];
  #pragma unroll
  for (int u = 0; u < 20; u++) s_h[u] = 0.f;
  float c_enc = 0.f;
  for (int t = 0; t < LEN; t++){
    v2 ac0 = (v2){ xp[t*80 + cA], xp[t*80 + cB] };
    v2 ac1 = (v2){0.f,0.f}, ac2 = (v2){0.f,0.f}, ac3 = (v2){0.f,0.f};
    #pragma unroll
    for (int u = 0; u < 20; u += 4){
      ac0 += s_h[u  ]*whp[u  ];
      ac1 += s_h[u+1]*whp[u+1];
      ac2 += s_h[u+2]*whp[u+2];
      ac3 += s_h[u+3]*whp[u+3];
    }
    v2 zp = (ac0 + ac1) + (ac2 + ac3);     // {zi,zf} lo-half / {zg,zo} hi-half
    float ox = __shfl_xor(zp.x, 32, 64);   // lane u gets zg
    float oy = __shfl_xor(zp.y, 32, 64);   // lane u gets zo
    float hval = 0.f;
    if (lane < 20){
      c_enc = sigm(zp.y)*c_enc + sigm(zp.x)*ftanh(ox);
      hval  = sigm(oy)*ftanh(c_enc);
      eoT[lane*EOS + t] = hval;
    }
    #pragma unroll
    for (int u = 0; u < 20; u++) s_h[u] = RL(hval, u);
  }
  __syncthreads();                         // [barrier 2/2] eoT ready

  // ---- per-lane eo rows + mem_proj rows -> registers ----
  const int l1 = (lane < 47) ? lane + 64 : lane;
  float er0[20], er1[20];
  #pragma unroll
  for (int u = 0; u < 20; u++){ er0[u] = eoT[u*EOS + lane]; er1[u] = eoT[u*EOS + l1]; }
  float mp0[10], mp1[10];
  #pragma unroll
  for (int a = 0; a < 10; a++){
    float m0 = bmv[a], m1 = bmv[a];
    #pragma unroll
    for (int u = 0; u < 20; u++){ m0 += er0[u]*Wm_s[u*10 + a]; m1 += er1[u]*Wm_s[u*10 + a]; }
    mp0[a] = m0; mp1[a] = m1;
  }

  // ---- decoder weights (pair layout) ----
  v2 dwxp[20], dwhp[20];
  #pragma unroll
  for (int u = 0; u < 20; u++){
    dwxp[u] = (v2){ dec_Wx[u*80 + cA], dec_Wx[u*80 + cB] };
    dwhp[u] = (v2){ dec_Wh[u*80 + cA], dec_Wh[u*80 + cB] };
  }
  const v2 dbp = (v2){ dec_b[cA], dec_b[cB] };
  float wq[20];
  if (lane < 10){
    #pragma unroll
    for (int u = 0; u < 20; u++) wq[u] = att_Wq[u*10 + lane];
  }

  float s_c[20];
  #pragma unroll
  for (int u = 0; u < 20; u++){ s_c[u] = 0.f; s_h[u] = 0.f; }

  // ================= decoder: barrier-free =================
  float ap0 = 0.f, ap1 = 0.f, c_dec = 0.f;
  for (int t = 0; t < TDEC; t++){
    // q = c @ att_Wq + bq (query from CELL state, per reference)
    float qv = bq_l;
    if (lane < 10){
      float qa = 0.f, qb = 0.f;
      #pragma unroll
      for (int u = 0; u < 20; u += 2){ qa += s_c[u]*wq[u]; qb += s_c[u+1]*wq[u+1]; }
      qv += qa + qb;
    }
    float s_q[10];
    #pragma unroll
    for (int a = 0; a < 10; a++) s_q[a] = RL(qv, a);

    // scores: sc = SB - 2*sum_a V_a * rcp(exp(2*pre_a)+1)   (inline loc-tanh)
    float r00 = 0.f, r01 = 0.f, r10 = 0.f, r11 = 0.f;
    #pragma unroll
    for (int a = 0; a < 10; a += 2){
      float pre0 = mp0[a]   + s_q[a]   + ftanh(wloc[a]*ap0);
      float pre1 = mp1[a]   + s_q[a]   + ftanh(wloc[a]*ap1);
      float pr20 = mp0[a+1] + s_q[a+1] + ftanh(wloc[a+1]*ap0);
      float pr21 = mp1[a+1] + s_q[a+1] + ftanh(wloc[a+1]*ap1);
      r00 += V[a]  *rcpf(__expf(2.0f*pre0) + 1.0f);
      r01 += V[a]  *rcpf(__expf(2.0f*pre1) + 1.0f);
      r10 += V[a+1]*rcpf(__expf(2.0f*pr20) + 1.0f);
      r11 += V[a+1]*rcpf(__expf(2.0f*pr21) + 1.0f);
    }
    // |sc| <= |bv|+sum|V| (~2): exp cannot overflow -> no max subtraction
    float e0 = __expf(SB - 2.0f*(r00 + r10));
    float e1 = (lane < 47) ? __expf(SB - 2.0f*(r01 + r11)) : 0.f;
    float inv = rcpf(wave_sum(e0 + e1));
    ap0 = e0*inv; ap1 = e1*inv;

    // ctx raw reduces (20 independent DPP trees; inv folded at the end)
    float ws[20];
    #pragma unroll
    for (int u = 0; u < 20; u++) ws[u] = wave_sum(e0*er0[u] + e1*er1[u]);

    // z pair = ctx@Wx + h@Wh + b: packed v2, 2-way split chains
    v2 zx0 = (v2){0.f,0.f}, zx1 = (v2){0.f,0.f};
    v2 zh0 = dbp,            zh1 = (v2){0.f,0.f};
    #pragma unroll
    for (int u = 0; u < 20; u += 2){
      zx0 += ws[u]   *dwxp[u];
      zx1 += ws[u+1] *dwxp[u+1];
      zh0 += s_h[u]  *dwhp[u];
      zh1 += s_h[u+1]*dwhp[u+1];
    }
    v2 zzh = zh0 + zh1;
    v2 zzx = zx0 + zx1;
    v2 zp;
    zp.x = zzh.x + zzx.x*inv;
    zp.y = zzh.y + zzx.y*inv;
    float ox = __shfl_xor(zp.x, 32, 64);   // zg for lanes<20
    float oy = __shfl_xor(zp.y, 32, 64);   // zo for lanes<20

    float hval = 0.f;
    if (lane < 20){
      c_dec = sigm(zp.y)*c_dec + sigm(zp.x)*ftanh(ox);
      hval  = sigm(oy)*ftanh(c_dec);
    }

    // state broadcast (feeds next step's q and zh)
    #pragma unroll
    for (int u = 0; u < 20; u++){ s_c[u] = RL(c_dec, u); s_h[u] = RL(hval, u); }

    // y output (dead-end, drains under next step's issue)
    float pv = wave_sum(hval*outw);
    if (lane == 0) g_out[(size_t)b*TDEC + t] = ftanh(pv + ob);
  }
}

extern "C" void kernel_launch(void* const* d_in, const int* in_sizes, int n_in,
                              void* d_out, int out_size, void* d_ws, size_t ws_size,
                              hipStream_t stream) {
  const float* g_in   = (const float*)d_in[0];
  const float* enc_Wx = (const float*)d_in[1];
  const float* enc_Wh = (const float*)d_in[2];
  const float* enc_b  = (const float*)d_in[3];
  const float* att_Wq = (const float*)d_in[4];
  const float* att_bq = (const float*)d_in[5];
  const float* att_Wm = (const float*)d_in[6];
  const float* att_bm = (const float*)d_in[7];
  const float* att_V  = (const float*)d_in[8];
  const float* att_bv = (const float*)d_in[9];
  const float* loc_Wc = (const float*)d_in[10];
  const float* loc_Wd = (const float*)d_in[11];
  const float* dec_Wx = (const float*)d_in[12];
  const float* dec_Wh = (const float*)d_in[13];
  const float* dec_b  = (const float*)d_in[14];
  const float* out_W  = (const float*)d_in[15];
  const float* out_b  = (const float*)d_in[16];
  float* g_out = (float*)d_out;

  hipLaunchKernelGGL(attn_rnn_kernel, dim3(NB), dim3(64), 0, stream,
                     g_in, enc_Wx, enc_Wh, enc_b, att_Wq, att_bq, att_Wm, att_bm,
                     att_V, att_bv, loc_Wc, loc_Wd, dec_Wx, dec_Wh, dec_b,
                     out_W, out_b, g_out);
}